// Round 3
// baseline (76.114 us; speedup 1.0000x reference)
//
#include <hip/hip_runtime.h>

typedef __attribute__((ext_vector_type(8))) short          short8_t;   // 8 bf16
typedef __attribute__((ext_vector_type(8))) unsigned short ushort8_t;
typedef __attribute__((ext_vector_type(4))) float          floatx4;

constexpr int N_ROWS = 8192;
constexpr int DIM    = 64;
constexpr int TILE   = 128;
constexpr int PANEL  = TILE * DIM;       // 8192 ushorts = 16 KiB per (panel, h/l)

// f32 -> bf16 round-to-nearest-even
__device__ __forceinline__ unsigned short bf16_rne(float f) {
    unsigned int u = __float_as_uint(f);
    u += 0x7FFFu + ((u >> 16) & 1u);
    return (unsigned short)(u >> 16);
}

// global(AS1) -> LDS(AS3) 16-byte async copy; LDS dest = uniform base + lane*16
typedef __attribute__((address_space(1))) unsigned int gu32;
typedef __attribute__((address_space(3))) unsigned int lu32;
__device__ __forceinline__ void gload16(const void* g, void* l) {
    __builtin_amdgcn_global_load_lds((gu32*)g, (lu32*)l, 16, 0, 0);
}

// ---------------------------------------------------------------------------
// Kernel 1: norms + hi/lo bf16 split, written PRE-SWIZZLED in panel-tile order.
// Panel p (128 rows), local row rl, chunk c (8 ushorts):
//   off = (rl*64 + c*8) ^ ((rl&7)*8)   (XOR on bits 3..5 -> bijective)
// Layout: Xs[p][2][8192] (hi then lo), same for Ys.
// ---------------------------------------------------------------------------
__global__ void __launch_bounds__(256)
split_norms_kernel(const float* __restrict__ X, const float* __restrict__ Y,
                   float* __restrict__ x2, float* __restrict__ y2,
                   unsigned short* __restrict__ Xs, unsigned short* __restrict__ Ys) {
    const int r  = blockIdx.x * 256 + threadIdx.x;
    const int p  = r >> 7;
    const int rl = r & 127;
    const int swz = (rl & 7) * 8;
    const size_t pb = (size_t)p * (2 * PANEL);

    const float4* xr = reinterpret_cast<const float4*>(X + (size_t)r * DIM);
    const float4* yr = reinterpret_cast<const float4*>(Y + (size_t)r * DIM);

    float sx = 0.f, sy = 0.f;
#pragma unroll
    for (int c = 0; c < 8; ++c) {
        const int off = (rl * DIM + c * 8) ^ swz;
        float f[8];
        ushort8_t hi, lo;

        *reinterpret_cast<float4*>(&f[0]) = xr[2 * c];
        *reinterpret_cast<float4*>(&f[4]) = xr[2 * c + 1];
#pragma unroll
        for (int e = 0; e < 8; ++e) {
            sx = fmaf(f[e], f[e], sx);
            unsigned short hh = bf16_rne(f[e]);
            hi[e] = hh;
            lo[e] = bf16_rne(f[e] - __uint_as_float((unsigned int)hh << 16));
        }
        *reinterpret_cast<ushort8_t*>(&Xs[pb + off])         = hi;
        *reinterpret_cast<ushort8_t*>(&Xs[pb + PANEL + off]) = lo;

        *reinterpret_cast<float4*>(&f[0]) = yr[2 * c];
        *reinterpret_cast<float4*>(&f[4]) = yr[2 * c + 1];
#pragma unroll
        for (int e = 0; e < 8; ++e) {
            sy = fmaf(f[e], f[e], sy);
            unsigned short hh = bf16_rne(f[e]);
            hi[e] = hh;
            lo[e] = bf16_rne(f[e] - __uint_as_float((unsigned int)hh << 16));
        }
        *reinterpret_cast<ushort8_t*>(&Ys[pb + off])         = hi;
        *reinterpret_cast<ushort8_t*>(&Ys[pb + PANEL + off]) = lo;
    }
    x2[r] = sx;
    y2[r] = sy;
}

// ---------------------------------------------------------------------------
// Kernel 2: split-bf16 MFMA, zero-VALU staging via global_load_lds.
// LDS quarters: [XH][XL][YH][YL], each 8192 ushorts (wave w stages quarter w).
// MFMA operands SWAPPED (A=Y frag, B=X frag) so lane regs span 4 output COLS
// -> float4 stores. Frag reuse: 16 ds_read_b128 per k-step for 48 MFMA.
// ---------------------------------------------------------------------------
__global__ void __launch_bounds__(256, 2)
rbf_mfma_kernel(const unsigned short* __restrict__ Xs,
                const unsigned short* __restrict__ Ys,
                const float* __restrict__ x2, const float* __restrict__ y2,
                float* __restrict__ out) {
    __shared__ unsigned short smem[4 * PANEL];   // 64 KiB

    const int tid  = threadIdx.x;
    const int lane = tid & 63;
    const int w    = tid >> 6;
    const int row0 = blockIdx.y * TILE;
    const int col0 = blockIdx.x * TILE;

    // ---- stage: wave w copies its 16 KiB quarter (16 x 1 KiB issues) ----
    {
        const unsigned short* src =
            (w < 2) ? Xs + (size_t)blockIdx.y * (2 * PANEL) + w * PANEL
                    : Ys + (size_t)blockIdx.x * (2 * PANEL) + (w & 1) * PANEL;
        unsigned short* dst = &smem[w * PANEL];
#pragma unroll
        for (int it = 0; it < 16; ++it)
            gload16(src + it * 512 + lane * 8, dst + it * 512);
    }
    __syncthreads();

    const int li = lane & 15;
    const int lg = lane >> 4;
    const int wr = (w >> 1) * 64;      // wave's X-row quadrant offset
    const int wc = (w & 1) * 64;       // wave's Y-row (output col) quadrant

    floatx4 acc[4][4] = {};

    // frag read: ushort idx = row*64 + ((ks*32 + lg*8) ^ ((row&7)*8)); row&7 == li&7
#define LDF(qbase, rowbase, koff)                                              \
    (*reinterpret_cast<const short8_t*>(                                       \
        &smem[(qbase) + ((rowbase) + li) * DIM + (koff)]))

#pragma unroll
    for (int ks = 0; ks < 2; ++ks) {
        const int koff = (ks * 32 + lg * 8) ^ ((li & 7) * 8);
        short8_t aH[4], bH[4], aL[4], bL[4];
#pragma unroll
        for (int mi = 0; mi < 4; ++mi) aH[mi] = LDF(0 * PANEL, wr + mi * 16, koff);
#pragma unroll
        for (int ni = 0; ni < 4; ++ni) bH[ni] = LDF(2 * PANEL, wc + ni * 16, koff);
#pragma unroll
        for (int mi = 0; mi < 4; ++mi)
#pragma unroll
            for (int ni = 0; ni < 4; ++ni)
                acc[mi][ni] = __builtin_amdgcn_mfma_f32_16x16x32_bf16(
                    bH[ni], aH[mi], acc[mi][ni], 0, 0, 0);   // Xh . Yh
#pragma unroll
        for (int ni = 0; ni < 4; ++ni) bL[ni] = LDF(3 * PANEL, wc + ni * 16, koff);
#pragma unroll
        for (int mi = 0; mi < 4; ++mi)
#pragma unroll
            for (int ni = 0; ni < 4; ++ni)
                acc[mi][ni] = __builtin_amdgcn_mfma_f32_16x16x32_bf16(
                    bL[ni], aH[mi], acc[mi][ni], 0, 0, 0);   // Xh . Yl
#pragma unroll
        for (int mi = 0; mi < 4; ++mi) aL[mi] = LDF(1 * PANEL, wr + mi * 16, koff);
#pragma unroll
        for (int mi = 0; mi < 4; ++mi)
#pragma unroll
            for (int ni = 0; ni < 4; ++ni)
                acc[mi][ni] = __builtin_amdgcn_mfma_f32_16x16x32_bf16(
                    bH[ni], aL[mi], acc[mi][ni], 0, 0, 0);   // Xl . Yh
    }
#undef LDF

    // ---- epilogue: lane (li,lg) reg j -> out[row0+wr+mi*16+li][col0+wc+ni*16+lg*4+j]
    const int orow = row0 + wr + li;
    const int ocol = col0 + wc + lg * 4;
#pragma unroll
    for (int mi = 0; mi < 4; ++mi) {
        const float xs = x2[orow + mi * 16];
        float* obase = out + (size_t)(orow + mi * 16) * N_ROWS + ocol;
#pragma unroll
        for (int ni = 0; ni < 4; ++ni) {
            const float4 yv = *reinterpret_cast<const float4*>(&y2[ocol + ni * 16]);
            float4 o;
            o.x = __expf(-fmaxf(fmaf(-2.f, acc[mi][ni][0], xs + yv.x), 0.f));
            o.y = __expf(-fmaxf(fmaf(-2.f, acc[mi][ni][1], xs + yv.y), 0.f));
            o.z = __expf(-fmaxf(fmaf(-2.f, acc[mi][ni][2], xs + yv.z), 0.f));
            o.w = __expf(-fmaxf(fmaf(-2.f, acc[mi][ni][3], xs + yv.w), 0.f));
            *reinterpret_cast<float4*>(obase + ni * 16) = o;
        }
    }
}

// ---------------------------------------------------------------------------
extern "C" void kernel_launch(void* const* d_in, const int* in_sizes, int n_in,
                              void* d_out, int out_size, void* d_ws, size_t ws_size,
                              hipStream_t stream) {
    const float* X = (const float*)d_in[0];
    const float* Y = (const float*)d_in[1];
    float* out = (float*)d_out;

    float* x2 = (float*)d_ws;                              // 8192 f32
    float* y2 = x2 + N_ROWS;                               // 8192 f32
    unsigned short* Xs = (unsigned short*)(y2 + N_ROWS);   // 64 panels x 2 x 16KiB = 2 MiB
    unsigned short* Ys = Xs + (N_ROWS / TILE) * 2 * PANEL; // 2 MiB

    split_norms_kernel<<<N_ROWS / 256, 256, 0, stream>>>(X, Y, x2, y2, Xs, Ys);

    dim3 grid(N_ROWS / TILE, N_ROWS / TILE);   // 64 x 64
    rbf_mfma_kernel<<<grid, 256, 0, stream>>>(Xs, Ys, x2, y2, out);
}

// Round 4
// 73.597 us; speedup vs baseline: 1.0342x; 1.0342x over previous
//
#include <hip/hip_runtime.h>

typedef __attribute__((ext_vector_type(8))) short          short8_t;   // 8 bf16
typedef __attribute__((ext_vector_type(8))) unsigned short ushort8_t;
typedef __attribute__((ext_vector_type(4))) float          floatx4;

constexpr int N_ROWS = 8192;
constexpr int DIM    = 64;
constexpr int PANEL  = 128 * DIM;   // 8192 ushorts = 16 KiB per (panel, hi/lo)

// f32 -> bf16 round-to-nearest-even
__device__ __forceinline__ unsigned short bf16_rne(float f) {
    unsigned int u = __float_as_uint(f);
    u += 0x7FFFu + ((u >> 16) & 1u);
    return (unsigned short)(u >> 16);
}

// ---------------------------------------------------------------------------
// Kernel 1: norms + hi/lo bf16 split, written in FRAGMENT order:
//   panel p (128 rows) -> group g = rl>>4, li = rl&15; k = ks*32 + lg*8 + e.
//   ushort offset within panel-half = ((g*2 + ks)*64 + lg*16 + li)*8 + e
// so the main kernel's per-(g,ks) fragment load is one contiguous 1-KiB
// wave-coalesced global_load_dwordx4 (lane = lg*16+li).
// Two threads per row (h = k-half); norm reduced with one shfl_xor.
// ---------------------------------------------------------------------------
__global__ void __launch_bounds__(256)
split_norms_kernel(const float* __restrict__ X, const float* __restrict__ Y,
                   float* __restrict__ x2, float* __restrict__ y2,
                   unsigned short* __restrict__ Xs, unsigned short* __restrict__ Ys) {
    const int t  = blockIdx.x * 256 + threadIdx.x;   // [0, 16384)
    const int r  = t >> 1;                           // row
    const int h  = t & 1;                            // k-half (== ks)
    const int p  = r >> 7;
    const int rl = r & 127;
    const int g  = rl >> 4;
    const int li = rl & 15;
    const size_t pb = (size_t)p * (2 * PANEL);

    const float4* xr = reinterpret_cast<const float4*>(X + (size_t)r * DIM + h * 32);
    const float4* yr = reinterpret_cast<const float4*>(Y + (size_t)r * DIM + h * 32);

    float sx = 0.f, sy = 0.f;
#pragma unroll
    for (int c = 0; c < 4; ++c) {                    // lg = c
        const int off = ((g * 2 + h) * 64 + c * 16 + li) * 8;
        float f[8];
        ushort8_t hi, lo;

        *reinterpret_cast<float4*>(&f[0]) = xr[2 * c];
        *reinterpret_cast<float4*>(&f[4]) = xr[2 * c + 1];
#pragma unroll
        for (int e = 0; e < 8; ++e) {
            sx = fmaf(f[e], f[e], sx);
            unsigned short hh = bf16_rne(f[e]);
            hi[e] = hh;
            lo[e] = bf16_rne(f[e] - __uint_as_float((unsigned int)hh << 16));
        }
        *reinterpret_cast<ushort8_t*>(&Xs[pb + off])         = hi;
        *reinterpret_cast<ushort8_t*>(&Xs[pb + PANEL + off]) = lo;

        *reinterpret_cast<float4*>(&f[0]) = yr[2 * c];
        *reinterpret_cast<float4*>(&f[4]) = yr[2 * c + 1];
#pragma unroll
        for (int e = 0; e < 8; ++e) {
            sy = fmaf(f[e], f[e], sy);
            unsigned short hh = bf16_rne(f[e]);
            hi[e] = hh;
            lo[e] = bf16_rne(f[e] - __uint_as_float((unsigned int)hh << 16));
        }
        *reinterpret_cast<ushort8_t*>(&Ys[pb + off])         = hi;
        *reinterpret_cast<ushort8_t*>(&Ys[pb + PANEL + off]) = lo;
    }
    sx += __shfl_xor(sx, 1);
    sy += __shfl_xor(sy, 1);
    if (h == 0) { x2[r] = sx; y2[r] = sy; }
}

// ---------------------------------------------------------------------------
// Kernel 2: one wave per 64x64 output tile. NO LDS, NO barrier.
// Fragments loaded straight from the fragment-ordered panels (L2-resident,
// 1 KiB contiguous per wave per load). 96 MFMA (Xh.Yh + Xh.Yl + Xl.Yh),
// operands swapped so each lane's 4 acc regs = 4 consecutive output columns
// -> float4 stores.
// ---------------------------------------------------------------------------
__global__ void __launch_bounds__(64)
rbf_mfma_kernel(const unsigned short* __restrict__ Xs,
                const unsigned short* __restrict__ Ys,
                const float* __restrict__ x2, const float* __restrict__ y2,
                float* __restrict__ out) {
    const int lane = threadIdx.x;
    const int row0 = blockIdx.y * 64;
    const int col0 = blockIdx.x * 64;
    const unsigned short* Xp = Xs + (size_t)(blockIdx.y >> 1) * (2 * PANEL);
    const unsigned short* Yp = Ys + (size_t)(blockIdx.x >> 1) * (2 * PANEL);
    const int gx0 = (blockIdx.y & 1) * 4;   // A row-groups gx0..gx0+3
    const int gy0 = (blockIdx.x & 1) * 4;   // B col-groups gy0..gy0+3

    floatx4 acc[4][4] = {};

#define GF(P, hl, g, ks)                                                       \
    (*reinterpret_cast<const short8_t*>(                                       \
        (P) + (hl) * PANEL + (((g) * 2 + (ks)) * 64 + lane) * 8))

#pragma unroll
    for (int ks = 0; ks < 2; ++ks) {
        short8_t aH[4], bH[4], aL[4], bL[4];
#pragma unroll
        for (int mi = 0; mi < 4; ++mi) aH[mi] = GF(Xp, 0, gx0 + mi, ks);
#pragma unroll
        for (int ni = 0; ni < 4; ++ni) bH[ni] = GF(Yp, 0, gy0 + ni, ks);
#pragma unroll
        for (int mi = 0; mi < 4; ++mi)
#pragma unroll
            for (int ni = 0; ni < 4; ++ni)
                acc[mi][ni] = __builtin_amdgcn_mfma_f32_16x16x32_bf16(
                    bH[ni], aH[mi], acc[mi][ni], 0, 0, 0);   // Xh . Yh
#pragma unroll
        for (int ni = 0; ni < 4; ++ni) bL[ni] = GF(Yp, 1, gy0 + ni, ks);
#pragma unroll
        for (int mi = 0; mi < 4; ++mi)
#pragma unroll
            for (int ni = 0; ni < 4; ++ni)
                acc[mi][ni] = __builtin_amdgcn_mfma_f32_16x16x32_bf16(
                    bL[ni], aH[mi], acc[mi][ni], 0, 0, 0);   // Xh . Yl
#pragma unroll
        for (int mi = 0; mi < 4; ++mi) aL[mi] = GF(Xp, 1, gx0 + mi, ks);
#pragma unroll
        for (int mi = 0; mi < 4; ++mi)
#pragma unroll
            for (int ni = 0; ni < 4; ++ni)
                acc[mi][ni] = __builtin_amdgcn_mfma_f32_16x16x32_bf16(
                    bH[ni], aL[mi], acc[mi][ni], 0, 0, 0);   // Xl . Yh
    }
#undef GF

    // ---- epilogue: lane (li,lg) reg j -> out[row0+mi*16+li][col0+ni*16+lg*4+j]
    const int li = lane & 15;
    const int lg = lane >> 4;
    const int orow = row0 + li;
    const int ocol = col0 + lg * 4;
#pragma unroll
    for (int mi = 0; mi < 4; ++mi) {
        const float xs = x2[orow + mi * 16];
        float* obase = out + (size_t)(orow + mi * 16) * N_ROWS + ocol;
#pragma unroll
        for (int ni = 0; ni < 4; ++ni) {
            const float4 yv = *reinterpret_cast<const float4*>(&y2[ocol + ni * 16]);
            float4 o;
            o.x = __expf(-fmaxf(fmaf(-2.f, acc[mi][ni][0], xs + yv.x), 0.f));
            o.y = __expf(-fmaxf(fmaf(-2.f, acc[mi][ni][1], xs + yv.y), 0.f));
            o.z = __expf(-fmaxf(fmaf(-2.f, acc[mi][ni][2], xs + yv.z), 0.f));
            o.w = __expf(-fmaxf(fmaf(-2.f, acc[mi][ni][3], xs + yv.w), 0.f));
            *reinterpret_cast<float4*>(obase + ni * 16) = o;
        }
    }
}

// ---------------------------------------------------------------------------
extern "C" void kernel_launch(void* const* d_in, const int* in_sizes, int n_in,
                              void* d_out, int out_size, void* d_ws, size_t ws_size,
                              hipStream_t stream) {
    const float* X = (const float*)d_in[0];
    const float* Y = (const float*)d_in[1];
    float* out = (float*)d_out;

    float* x2 = (float*)d_ws;                              // 8192 f32
    float* y2 = x2 + N_ROWS;                               // 8192 f32
    unsigned short* Xs = (unsigned short*)(y2 + N_ROWS);   // 2 MiB
    unsigned short* Ys = Xs + (N_ROWS / 128) * 2 * PANEL;  // 2 MiB

    split_norms_kernel<<<(2 * N_ROWS) / 256, 256, 0, stream>>>(X, Y, x2, y2, Xs, Ys);

    dim3 grid(N_ROWS / 64, N_ROWS / 64);   // 128 x 128 one-wave blocks
    rbf_mfma_kernel<<<grid, 64, 0, stream>>>(Xs, Ys, x2, y2, out);
}